// Round 7
// baseline (228.958 us; speedup 1.0000x reference)
//
#include <hip/hip_runtime.h>
#include <math.h>

// ModifiedAttention bf16-MFMA pipeline v12: B=4,S=1024,D=768,H=24,DH=64,DG=1
//  - attn: NEW -- V staging to LDS dropped (m169 lesson: LDS-staging L2-fit
//    data is pure overhead). V fragments read per-lane straight from global
//    (L2-resident, 3MB/XCD after remap), issued at iter START and consumed
//    only after QK^T+softmax (~500cyc cover vs ~200cyc L2 latency; T14).
//    K stays LDS-staged (needed immediately after barrier -- R4 lesson).
//    LDS 41984->25856B; LDS-pipe ops/iter/wave 34->24.
//    Verified: direct read vf[c][dt]=Vt[(dt*16+lr)*SS+kt*64+(c*4+lq)*8] is
//    bit-identical to the old swizzled-LDS path (swizzle cancels).
//  - prep fused 6->2 (R6: -10us). qkv: v7 2-phase dbuf + XCD swizzle (ceiling
//    for this structure; BK=32 and B-from-global both regressed). out_gemm:
//    dbuf + XCD chunking. Gates folded into qkv; max-free softmax.

namespace {

typedef short bf16x8 __attribute__((ext_vector_type(8)));
typedef float f32x4 __attribute__((ext_vector_type(4)));
typedef unsigned short u16;
typedef u16 u16x8 __attribute__((ext_vector_type(8)));
typedef unsigned int u32;

constexpr int BB = 4, SS = 1024, DD = 768, HH = 24;
constexpr int RR = BB * SS;     // 4096
constexpr int NC = HH * 64;     // 1536
constexpr int NQKV = 3 * NC;    // 4608
constexpr int NTOT = NQKV + 128; // + gate block

__device__ inline u16 f2bf(float f) {   // RNE fp32 -> bf16
    u32 u = __float_as_uint(f);
    u += 0x7FFFu + ((u >> 16) & 1u);
    return (u16)(u >> 16);
}

// async global->LDS, 16B/lane; LDS base MUST be wave-uniform (HW scatters lane*16)
__device__ __forceinline__ void async16(const void* g, const void* lds) {
    __builtin_amdgcn_global_load_lds(
        (const __attribute__((address_space(1))) u32*)(unsigned long long)(size_t)g,
        (__attribute__((address_space(3))) u32*)(u32)(size_t)lds, 16, 0, 0);
}

// ---------------- fused prep A: norms (blocks [0,1536)) + x2bf ([1536,4608)) ----------------
__global__ __launch_bounds__(256)
void prep_a_kernel(const float* __restrict__ Wv, const float* __restrict__ Wo,
                   float* __restrict__ invV, float* __restrict__ invO,
                   const float* __restrict__ x, u16* __restrict__ xb) {
    const int bid = blockIdx.x;
    if (bid < NC) {                        // ---- norms ----
        int j = bid;                       // (h,dh) flat, 1536
        int h = j >> 6, dh = j & 63;
        __shared__ float sv[256], so[256];
        float av = 0.f, ao = 0.f;
        for (int d = threadIdx.x; d < DD; d += 256) {
            float a = Wv[(h * DD + d) * 64 + dh];    // W_V[h,d,dh], norm over d
            av += a * a;
            float b = Wo[(size_t)j * DD + d];        // W_O[h,dh,d], norm over d
            ao += b * b;
        }
        sv[threadIdx.x] = av; so[threadIdx.x] = ao;
        __syncthreads();
        for (int s = 128; s > 0; s >>= 1) {
            if (threadIdx.x < s) {
                sv[threadIdx.x] += sv[threadIdx.x + s];
                so[threadIdx.x] += so[threadIdx.x + s];
            }
            __syncthreads();
        }
        if (threadIdx.x == 0) {
            invV[j] = 1.f / fmaxf(sqrtf(sv[0]), 1e-12f);
            invO[j] = 1.f / fmaxf(sqrtf(so[0]), 1e-12f);
        }
    } else {                               // ---- x -> bf16 ----
        int idx = (bid - NC) * 256 + threadIdx.x;   // RR*DD/4 float4s
        float4 v = ((const float4*)x)[idx];
        ushort4 o;
        o.x = f2bf(v.x); o.y = f2bf(v.y); o.z = f2bf(v.z); o.w = f2bf(v.w);
        ((ushort4*)xb)[idx] = o;
    }
}

// ---------------- fused prep B: pack_wqkv [0,864) | pack_wo [864,1152) |
//                  pack_gates [1152,1280) | pack_bias [1280,1298) ----------------
__global__ __launch_bounds__(256)
void prep_b_kernel(const float* __restrict__ Wq, const float* __restrict__ Wk,
                   const float* __restrict__ Wv, const float* __restrict__ invV,
                   u16* __restrict__ wT,
                   const float* __restrict__ Wo, u16* __restrict__ woT,
                   const float* __restrict__ Wgq, const float* __restrict__ Wgk,
                   const float* __restrict__ bq, const float* __restrict__ bk,
                   const float* __restrict__ bv, float* __restrict__ biasp) {
    const int bid = blockIdx.x;
    const int t = threadIdx.x;
    __shared__ float sT[64][68];

    if (bid < 864) {                       // ---- pack W_{Q,K,V} -> wT rows [0,4608) ----
        const int bx = bid % 12, h = (bid / 12) % 24, p = bid / 288;
        const int k0 = bx * 64;
        const float* W = (p == 0 ? Wq : p == 1 ? Wk : Wv) + (size_t)h * DD * 64;
#pragma unroll
        for (int rep = 0; rep < 4; rep++) {
            int idx = t + rep * 256; int kk = idx >> 4, c = idx & 15;
            *(float4*)&sT[kk][c * 4] = *(const float4*)&W[(size_t)(k0 + kk) * 64 + c * 4];
        }
        __syncthreads();
#pragma unroll
        for (int rep = 0; rep < 2; rep++) {
            int idx = t + rep * 256; int dh = idx >> 3, cj = idx & 7;
            float sc = (p == 2) ? invV[h * 64 + dh] : 1.f;
            u16x8 o;
#pragma unroll
            for (int i = 0; i < 8; i++) o[i] = f2bf(sT[cj * 8 + i][dh] * sc);
            *(u16x8*)&wT[(size_t)(p * NC + h * 64 + dh) * DD + k0 + cj * 8] = o;
        }
    } else if (bid < 1152) {               // ---- pack W_O -> woT [768 d][1536 j] ----
        const int id2 = bid - 864;
        const int j0 = (id2 % 24) * 64, d0 = (id2 / 24) * 64;
#pragma unroll
        for (int rep = 0; rep < 4; rep++) {
            int idx = t + rep * 256; int jj = idx >> 4, c = idx & 15;
            *(float4*)&sT[jj][c * 4] = *(const float4*)&Wo[(size_t)(j0 + jj) * DD + d0 + c * 4];
        }
        __syncthreads();
#pragma unroll
        for (int rep = 0; rep < 2; rep++) {
            int idx = t + rep * 256; int dd = idx >> 3, cj = idx & 7;
            u16x8 o;
#pragma unroll
            for (int i = 0; i < 8; i++) o[i] = f2bf(sT[cj * 8 + i][dd]);
            *(u16x8*)&woT[(size_t)(d0 + dd) * NC + j0 + cj * 8] = o;
        }
    } else if (bid < 1280) {               // ---- pack gate weights -> wT rows [4608,4736) ----
        int g = bid - 1152;                // 0..127
        u16* dst = wT + (size_t)(NQKV + g) * DD;
        if (g < 48) {
            const float* src = ((g & 1) ? Wgk : Wgq) + (size_t)(g >> 1) * DD;
            for (int c = t; c < DD; c += 256) dst[c] = f2bf(src[c]);
        } else {
            for (int c = t; c < DD; c += 256) dst[c] = 0;
        }
    } else {                               // ---- pack bias ----
        int n = (bid - 1280) * 256 + t;
        if (n < NQKV) {
            int p = n / NC, rem = n % NC;
            biasp[n] = (p == 0) ? bq[rem] : (p == 1) ? bk[rem] : bv[rem];
        }
    }
}

// ---------------- qkv+gates MFMA GEMM: C[4096,4736] = xb @ wT^T ----------------
// v7: dbuf prefetch + XCD-chunked swizzle. Grid 1D 1184 blocks:
//   xcd = bid%8, idx = bid/8  ->  rb = xcd*148 + idx  (contiguous per XCD)
//   band = rb/296 (8 rows x 37 cols), col-major within band.
__global__ __launch_bounds__(256)
void qkv_gemm_kernel(const u16* __restrict__ xb, const u16* __restrict__ wT,
                     const float* __restrict__ biasp,
                     const float* __restrict__ bgq, const float* __restrict__ bgk,
                     u16* __restrict__ qo, u16* __restrict__ ko, u16* __restrict__ vto,
                     float* __restrict__ qgo, float* __restrict__ kgo) {
    const int bid = blockIdx.x;            // 0..1183 (= 8*148)
    const int rb = (bid & 7) * 148 + (bid >> 3);
    const int band = rb / 296, r2 = rb % 296;   // band: 8 rows x 37 cols
    const int bx = r2 >> 3, by = band * 8 + (r2 & 7);
    const int n0 = bx * 128, row0 = by * 128;

    const int t = threadIdx.x, w = t >> 6, l = t & 63, lr = l & 15, lq = l >> 4;
    const int wr = (w >> 1) * 64, wc = (w & 1) * 64;
    __shared__ u16 smem[2 * 16384];   // dbuf: [buf][sA 16KB | sB 16KB]; epi reuses 36KB

    const int src_row = l >> 3;            // 0..7 within 8-row chunk
    const int cbs = (l & 7) ^ src_row;     // swizzled source col-block
    const int swz = lr & 7;                // read-side swizzle

    auto stage = [&](int k0, int buf) {
        u16* sA = smem + buf * 16384;
        u16* sB = sA + 8192;
#pragma unroll
        for (int i = 0; i < 4; i++) {
            int ch = w * 4 + i;            // 16 chunks of 8 rows each
            int rowA = ch * 8 + src_row;
            async16(xb + (size_t)(row0 + rowA) * DD + k0 + cbs * 8, sA + ch * 512);
            async16(wT + (size_t)(n0 + rowA) * DD + k0 + cbs * 8, sB + ch * 512);
        }
    };

    stage(0, 0);
    int cur = 0;
    f32x4 acc[4][4] = {};
    for (int k0 = 0; k0 < DD; k0 += 64) {
        __syncthreads();                   // buf[cur] loads drained; prev reads done
        if (k0 + 64 < DD) stage(k0 + 64, cur ^ 1);
        const u16* sA = smem + cur * 16384;
        const u16* sB = sA + 8192;
#pragma unroll
        for (int s = 0; s < 2; s++) {
            const int j8 = ((s * 4 + lq) ^ swz) * 8;
            bf16x8 af[4], bf[4];
#pragma unroll
            for (int i = 0; i < 4; i++) {
                af[i] = *(const bf16x8*)&sA[(wr + i * 16 + lr) * 64 + j8];
                bf[i] = *(const bf16x8*)&sB[(wc + i * 16 + lr) * 64 + j8];
            }
#pragma unroll
            for (int mt = 0; mt < 4; mt++)
#pragma unroll
                for (int nt = 0; nt < 4; nt++)
                    acc[mt][nt] = __builtin_amdgcn_mfma_f32_16x16x32_bf16(
                        af[mt], bf[nt], acc[mt][nt], 0, 0, 0);
        }
        cur ^= 1;
    }
    __syncthreads();                       // frag reads done before LDS reuse

    const int p = n0 / NC;                 // 0..3 (3 = gate block)
    const int b = row0 >> 10, s0 = row0 & (SS - 1);

    if (p == 3) {                          // gates: cols j = nt*16+lr < 48
        if (wc == 0) {
#pragma unroll
            for (int nt = 0; nt < 3; nt++) {
                int j = nt * 16 + lr, hh = j >> 1;
                float bias = (j & 1) ? bgk[hh] : bgq[hh];
                float* dst = (j & 1) ? kgo : qgo;
#pragma unroll
                for (int mt = 0; mt < 4; mt++)
#pragma unroll
                    for (int r = 0; r < 4; r++)
                        dst[((size_t)b * HH + hh) * SS + s0 + wr + mt * 16 + lq * 4 + r] =
                            acc[mt][nt][r] + bias;
            }
        }
        return;
    }

    const int cq = n0 + wc, srow = s0 + wr;
    u16* tw = smem + w * 4608;             // per-wave 64 x 72 region
    float bb[4];
#pragma unroll
    for (int nt = 0; nt < 4; nt++) bb[nt] = biasp[cq + nt * 16 + lr];

    if (p < 2) {                           // q or k: layout [s][dh]
        const float sc = (p == 0) ? 0.125f : 1.f;   // fold 1/sqrt(64) into q
#pragma unroll
        for (int mt = 0; mt < 4; mt++)
#pragma unroll
            for (int nt = 0; nt < 4; nt++)
#pragma unroll
                for (int r = 0; r < 4; r++)
                    tw[(mt * 16 + lq * 4 + r) * 72 + nt * 16 + lr] =
                        f2bf((acc[mt][nt][r] + bb[nt]) * sc);
        const int h = (cq - p * NC) >> 6;
        u16* dst = (p == 0 ? qo : ko) + ((size_t)(b * HH + h) * SS + srow) * 64;
#pragma unroll
        for (int c = 0; c < 8; c++)
            *(u16x8*)&dst[(size_t)l * 64 + c * 8] = *(const u16x8*)&tw[l * 72 + c * 8];
    } else {                               // v: transpose to [dh][s]
#pragma unroll
        for (int mt = 0; mt < 4; mt++)
#pragma unroll
            for (int nt = 0; nt < 4; nt++)
#pragma unroll
                for (int r = 0; r < 4; r++)
                    tw[(nt * 16 + lr) * 72 + mt * 16 + lq * 4 + r] =
                        f2bf(acc[mt][nt][r] + bb[nt]);
        const int h = (cq - 2 * NC) >> 6;
        u16* dst = vto + ((size_t)(b * HH + h) * 64 + l) * SS + srow;
#pragma unroll
        for (int c = 0; c < 8; c++)
            *(u16x8*)&dst[c * 8] = *(const u16x8*)&tw[l * 72 + c * 8];
    }
}

// ---------------- MFMA flash attention, K-staged + V-direct-from-global ----------------
// v12: 1D grid 768, XCD-aware remap (all 8 pr-blocks of a (b,h) on one XCD;
// 12 bh x 256KB = 3MB fits 4MB L2). V is NOT staged: 8 per-lane b128 global
// loads issued at iter start, consumed after QK^T+softmax (T14 issue-early).
// Bit-identical to old LDS path (write/read swizzles cancel).
__global__ __launch_bounds__(256)
void attn_kernel(const u16* __restrict__ qb, const u16* __restrict__ kb,
                 const u16* __restrict__ vtb, const float* __restrict__ qg,
                 const float* __restrict__ kg, const float* __restrict__ invO,
                 u16* __restrict__ z) {
    const int bid = blockIdx.x;            // 0..767
    const int xcd = bid & 7, idx = bid >> 3;
    const int hb = xcd * 12 + (idx >> 3);  // 0..95
    const int pr = idx & 7;
    const int h = hb % HH, b = hb / HH;
    const int t = threadIdx.x, w = t >> 6, l = t & 63, lr = l & 15, lq = l >> 4;

    __shared__ u16 sK[2][64 * 64];
    __shared__ u16 sP[4][16 * 72];
    u16* tP = sP[w];

    const size_t bh = (size_t)(b * HH + h);
    const u16* Kb = kb + bh * SS * 64;
    const u16* Vt = vtb + bh * 64 * SS;
    const float* kgb = kg + bh * SS;

    const int src_row = l >> 3;
    const int cbs = (l & 7) ^ src_row;
    const int swz = lr & 7;

    auto stage = [&](int kt, int buf) {
#pragma unroll
        for (int i = 0; i < 2; i++) {
            int kc = w * 2 + i;            // 8 chunks x 8 rows; LDS base wave-uniform
            int row = kc * 8 + src_row;
            async16(Kb + ((size_t)(kt * 64 + row)) * 64 + cbs * 8, sK[buf] + kc * 512);
        }
    };

    stage(0, 0);
    int cur = 0;
#pragma unroll
    for (int sub = 0; sub < 2; sub++) {
        const int QT = sub ? (15 - pr) : pr;
        const int q0 = QT * 64 + w * 16;   // wave's first q row
        const u16* Qw = qb + (bh * SS + q0) * 64;
        bf16x8 aq0 = *(const bf16x8*)(Qw + (size_t)lr * 64 + lq * 8);
        bf16x8 aq1 = *(const bf16x8*)(Qw + (size_t)lr * 64 + 32 + lq * 8);
        float qgr[4];
#pragma unroll
        for (int r = 0; r < 4; r++) qgr[r] = qg[bh * SS + q0 + lq * 4 + r];

        f32x4 o[4] = {};
        float lacc[4] = {};

        for (int kt = 0; kt <= QT; kt++) {
            __syncthreads();               // K buf[cur] loads drained; prev reads done
            if (kt < QT) stage(kt + 1, cur ^ 1);
            else if (sub == 0) stage(0, cur ^ 1);
            const u16* K_ = sK[cur];

            // V fragments: per-lane global loads, issued NOW, used after
            // QK^T+softmax (~500cyc cover). L2-resident via XCD remap.
            bf16x8 vf[2][4];
#pragma unroll
            for (int c = 0; c < 2; c++)
#pragma unroll
                for (int dt = 0; dt < 4; dt++)
                    vf[c][dt] = *(const bf16x8*)&Vt[(size_t)(dt * 16 + lr) * SS +
                                                    kt * 64 + (c * 4 + lq) * 8];

            // kg values straight from global (L2-resident)
            float kgv[4];
#pragma unroll
            for (int nt = 0; nt < 4; nt++) kgv[nt] = kgb[kt * 64 + nt * 16 + lr];

            // S = Q K^T (q pre-scaled by 1/sqrt(64))
            f32x4 sf[4] = {};
#pragma unroll
            for (int s = 0; s < 2; s++) {
                const int j8 = ((s * 4 + lq) ^ swz) * 8;
                const bf16x8 aqs = s ? aq1 : aq0;
#pragma unroll
                for (int nt = 0; nt < 4; nt++) {
                    bf16x8 bk = *(const bf16x8*)&K_[(nt * 16 + lr) * 64 + j8];
                    sf[nt] = __builtin_amdgcn_mfma_f32_16x16x32_bf16(aqs, bk, sf[nt], 0, 0, 0);
                }
            }
            if (kt == QT) {                // diagonal tile: causal mask
#pragma unroll
                for (int nt = 0; nt < 4; nt++)
#pragma unroll
                    for (int r = 0; r < 4; r++)
                        if (nt * 16 + lr > w * 16 + lq * 4 + r) sf[nt][r] = -INFINITY;
            }

            // p = exp(s); l += p; P_gated -> wave-local LDS (bf16)
#pragma unroll
            for (int nt = 0; nt < 4; nt++)
#pragma unroll
                for (int r = 0; r < 4; r++) {
                    float pv = __expf(sf[nt][r]);
                    lacc[r] += pv;
                    float g = fminf(fmaxf(qgr[r] * kgv[nt], 0.f), 1.f);
                    tP[(lq * 4 + r) * 72 + nt * 16 + lr] = f2bf(pv * g);
                }

            // O += P V (wave-local tP: no barrier; V from registers)
#pragma unroll
            for (int c = 0; c < 2; c++) {
                bf16x8 ap = *(const bf16x8*)&tP[lr * 72 + c * 32 + lq * 8];
#pragma unroll
                for (int dt = 0; dt < 4; dt++)
                    o[dt] = __builtin_amdgcn_mfma_f32_16x16x32_bf16(ap, vf[c][dt], o[dt], 0, 0, 0);
            }
            cur ^= 1;
        }

        // final l reduction across the 16 lanes sharing each q-row
#pragma unroll
        for (int r = 0; r < 4; r++) {
            float v = lacc[r];
            v += __shfl_xor(v, 1);
            v += __shfl_xor(v, 2);
            v += __shfl_xor(v, 4);
            v += __shfl_xor(v, 8);
            lacc[r] = __builtin_amdgcn_rcpf(v);
        }

        // epilogue: z = (o/l)*invO -> bf16 [B,S,1536]
        const int col0 = h * 64;
#pragma unroll
        for (int dt = 0; dt < 4; dt++) {
            float io = invO[col0 + dt * 16 + lr];
#pragma unroll
            for (int r = 0; r < 4; r++) {
                float val = o[dt][r] * lacc[r] * io;
                z[((size_t)b * SS + q0 + lq * 4 + r) * NC + col0 + dt * 16 + lr] = f2bf(val);
            }
        }
    }
}

// ---------------- out MFMA GEMM: out[4096,768] = z[4096,1536] @ woT[d][j]^T ----------------
// 64x64 tiles, 1D grid 768 = 8*96, XCD-chunked: each XCD gets 8 rows x 12
// cols (woT 2.4MB + 8 zb panels 1.6MB fits 4MB L2); row-major within chunk.
__global__ __launch_bounds__(256)
void out_gemm_kernel(const u16* __restrict__ zb, const u16* __restrict__ woT,
                     float* __restrict__ out) {
    const int bid = blockIdx.x;            // 0..767 (= 8*96)
    const int rb = (bid & 7) * 96 + (bid >> 3);
    const int bx = rb % 12, by = rb / 12;
    const int n0 = bx * 64, row0 = by * 64;

    const int t = threadIdx.x, w = t >> 6, l = t & 63, lr = l & 15, lq = l >> 4;
    const int wr = (w >> 1) * 32, wc = (w & 1) * 32;
    __shared__ u16 sA[2][64 * 64], sB[2][64 * 64];

    const int src_row = l >> 3;
    const int cbs = (l & 7) ^ src_row;
    const int swz = lr & 7;

    auto stage = [&](int k0, int buf) {
#pragma unroll
        for (int i = 0; i < 2; i++) {
            int ch = w * 2 + i;
            int row = ch * 8 + src_row;
            async16(zb + (size_t)(row0 + row) * NC + k0 + cbs * 8, sA[buf] + ch * 512);
            async16(woT + (size_t)(n0 + row) * NC + k0 + cbs * 8, sB[buf] + ch * 512);
        }
    };

    stage(0, 0);
    int cur = 0;
    f32x4 acc[2][2] = {};
    for (int k0 = 0; k0 < NC; k0 += 64) {
        __syncthreads();
        if (k0 + 64 < NC) stage(k0 + 64, cur ^ 1);
#pragma unroll
        for (int s = 0; s < 2; s++) {
            const int j8 = ((s * 4 + lq) ^ swz) * 8;
            bf16x8 af[2], bf[2];
#pragma unroll
            for (int i = 0; i < 2; i++) {
                af[i] = *(const bf16x8*)&sA[cur][(wr + i * 16 + lr) * 64 + j8];
                bf[i] = *(const bf16x8*)&sB[cur][(wc + i * 16 + lr) * 64 + j8];
            }
#pragma unroll
            for (int mt = 0; mt < 2; mt++)
#pragma unroll
                for (int nt = 0; nt < 2; nt++)
                    acc[mt][nt] = __builtin_amdgcn_mfma_f32_16x16x32_bf16(
                        af[mt], bf[nt], acc[mt][nt], 0, 0, 0);
        }
        cur ^= 1;
    }
#pragma unroll
    for (int mt = 0; mt < 2; mt++)
#pragma unroll
        for (int nt = 0; nt < 2; nt++)
#pragma unroll
            for (int r = 0; r < 4; r++)
                out[(size_t)(row0 + wr + mt * 16 + lq * 4 + r) * DD + n0 + wc + nt * 16 + lr] =
                    acc[mt][nt][r];
}

}  // namespace

extern "C" void kernel_launch(void* const* d_in, const int* in_sizes, int n_in,
                              void* d_out, int out_size, void* d_ws, size_t ws_size,
                              hipStream_t stream) {
    const float* x   = (const float*)d_in[0];
    const float* W_Q = (const float*)d_in[1];
    const float* W_K = (const float*)d_in[2];
    const float* W_V = (const float*)d_in[3];
    const float* W_O = (const float*)d_in[4];
    const float* b_Q = (const float*)d_in[5];
    const float* b_K = (const float*)d_in[6];
    const float* b_V = (const float*)d_in[7];
    const float* Wgq = (const float*)d_in[8];
    const float* Wgk = (const float*)d_in[9];
    const float* bgq = (const float*)d_in[10];
    const float* bgk = (const float*)d_in[11];
    float* out = (float*)d_out;

    char* wsb = (char*)d_ws;
    auto alloc = [&](size_t bytes) -> char* {
        char* p = wsb;
        wsb += (bytes + 255) & ~(size_t)255;
        return p;
    };
    float* invV  = (float*)alloc((size_t)NC * 4);
    float* invO  = (float*)alloc((size_t)NC * 4);
    float* biasp = (float*)alloc((size_t)NQKV * 4);
    float* qg    = (float*)alloc((size_t)RR * HH * 4);
    float* kg    = (float*)alloc((size_t)RR * HH * 4);
    u16* xb      = (u16*)alloc((size_t)RR * DD * 2);
    u16* wT      = (u16*)alloc((size_t)NTOT * DD * 2);
    u16* woT     = (u16*)alloc((size_t)DD * NC * 2);
    u16* qb      = (u16*)alloc((size_t)RR * 64 * HH * 2);
    u16* kb      = (u16*)alloc((size_t)RR * 64 * HH * 2);
    u16* vtb     = (u16*)alloc((size_t)RR * 64 * HH * 2);
    u16* zb      = (u16*)alloc((size_t)RR * NC * 2);

    prep_a_kernel<<<NC + RR * DD / 4 / 256, 256, 0, stream>>>(
        W_V, W_O, invV, invO, x, xb);
    prep_b_kernel<<<1298, 256, 0, stream>>>(
        W_Q, W_K, W_V, invV, wT, W_O, woT, Wgq, Wgk, b_Q, b_K, b_V, biasp);
    qkv_gemm_kernel<<<NTOT / 128 * (RR / 128), 256, 0, stream>>>(
        xb, wT, biasp, bgq, bgk, qb, kb, vtb, qg, kg);
    attn_kernel<<<768, 256, 0, stream>>>(
        qb, kb, vtb, qg, kg, invO, zb);
    out_gemm_kernel<<<DD / 64 * (RR / 64), 256, 0, stream>>>(zb, woT, out);
}

// Round 8
// 207.330 us; speedup vs baseline: 1.1043x; 1.1043x over previous
//
#include <hip/hip_runtime.h>
#include <math.h>

// ModifiedAttention bf16-MFMA pipeline v13: B=4,S=1024,D=768,H=24,DH=64,DG=1
//  - attn: REVERTED to v11 (V staged in LDS; R7's V-direct regressed +22us:
//    per-lane V loads touch 16 cache lines/instr -> VMEM-issue bound,
//    MfmaUtil 8%. LDS staging was load-bearing). XCD remap kept.
//  - out_gemm: NEW 128x96 tiles (was 64x64 = the measured worst point of the
//    tile ladder, m92: 343 vs 912 TF). Grid 32x8 = 256 blocks = exactly 1/CU,
//    zero tail; 24 MFMA + 7 ds_read per wave-step (was 8+8); LDS 57.3KB dbuf;
//    XCD-chunked: 4 A-panels (1.5MB) + woT (2.4MB) = 3.9MB fits 4MB L2.
//  - qkv: v7 2-phase dbuf + XCD swizzle (structure ceiling; R3/R4 regressions).
//  - preps fused 6->2 (R6, -10us). Gates folded into qkv; max-free softmax.

namespace {

typedef short bf16x8 __attribute__((ext_vector_type(8)));
typedef float f32x4 __attribute__((ext_vector_type(4)));
typedef unsigned short u16;
typedef u16 u16x8 __attribute__((ext_vector_type(8)));
typedef unsigned int u32;

constexpr int BB = 4, SS = 1024, DD = 768, HH = 24;
constexpr int RR = BB * SS;     // 4096
constexpr int NC = HH * 64;     // 1536
constexpr int NQKV = 3 * NC;    // 4608
constexpr int NTOT = NQKV + 128; // + gate block

__device__ inline u16 f2bf(float f) {   // RNE fp32 -> bf16
    u32 u = __float_as_uint(f);
    u += 0x7FFFu + ((u >> 16) & 1u);
    return (u16)(u >> 16);
}

// async global->LDS, 16B/lane; LDS base MUST be wave-uniform (HW scatters lane*16)
__device__ __forceinline__ void async16(const void* g, const void* lds) {
    __builtin_amdgcn_global_load_lds(
        (const __attribute__((address_space(1))) u32*)(unsigned long long)(size_t)g,
        (__attribute__((address_space(3))) u32*)(u32)(size_t)lds, 16, 0, 0);
}

// ---------------- fused prep A: norms (blocks [0,1536)) + x2bf ([1536,4608)) ----------------
__global__ __launch_bounds__(256)
void prep_a_kernel(const float* __restrict__ Wv, const float* __restrict__ Wo,
                   float* __restrict__ invV, float* __restrict__ invO,
                   const float* __restrict__ x, u16* __restrict__ xb) {
    const int bid = blockIdx.x;
    if (bid < NC) {                        // ---- norms ----
        int j = bid;                       // (h,dh) flat, 1536
        int h = j >> 6, dh = j & 63;
        __shared__ float sv[256], so[256];
        float av = 0.f, ao = 0.f;
        for (int d = threadIdx.x; d < DD; d += 256) {
            float a = Wv[(h * DD + d) * 64 + dh];    // W_V[h,d,dh], norm over d
            av += a * a;
            float b = Wo[(size_t)j * DD + d];        // W_O[h,dh,d], norm over d
            ao += b * b;
        }
        sv[threadIdx.x] = av; so[threadIdx.x] = ao;
        __syncthreads();
        for (int s = 128; s > 0; s >>= 1) {
            if (threadIdx.x < s) {
                sv[threadIdx.x] += sv[threadIdx.x + s];
                so[threadIdx.x] += so[threadIdx.x + s];
            }
            __syncthreads();
        }
        if (threadIdx.x == 0) {
            invV[j] = 1.f / fmaxf(sqrtf(sv[0]), 1e-12f);
            invO[j] = 1.f / fmaxf(sqrtf(so[0]), 1e-12f);
        }
    } else {                               // ---- x -> bf16 ----
        int idx = (bid - NC) * 256 + threadIdx.x;   // RR*DD/4 float4s
        float4 v = ((const float4*)x)[idx];
        ushort4 o;
        o.x = f2bf(v.x); o.y = f2bf(v.y); o.z = f2bf(v.z); o.w = f2bf(v.w);
        ((ushort4*)xb)[idx] = o;
    }
}

// ---------------- fused prep B: pack_wqkv [0,864) | pack_wo [864,1152) |
//                  pack_gates [1152,1280) | pack_bias [1280,1298) ----------------
__global__ __launch_bounds__(256)
void prep_b_kernel(const float* __restrict__ Wq, const float* __restrict__ Wk,
                   const float* __restrict__ Wv, const float* __restrict__ invV,
                   u16* __restrict__ wT,
                   const float* __restrict__ Wo, u16* __restrict__ woT,
                   const float* __restrict__ Wgq, const float* __restrict__ Wgk,
                   const float* __restrict__ bq, const float* __restrict__ bk,
                   const float* __restrict__ bv, float* __restrict__ biasp) {
    const int bid = blockIdx.x;
    const int t = threadIdx.x;
    __shared__ float sT[64][68];

    if (bid < 864) {                       // ---- pack W_{Q,K,V} -> wT rows [0,4608) ----
        const int bx = bid % 12, h = (bid / 12) % 24, p = bid / 288;
        const int k0 = bx * 64;
        const float* W = (p == 0 ? Wq : p == 1 ? Wk : Wv) + (size_t)h * DD * 64;
#pragma unroll
        for (int rep = 0; rep < 4; rep++) {
            int idx = t + rep * 256; int kk = idx >> 4, c = idx & 15;
            *(float4*)&sT[kk][c * 4] = *(const float4*)&W[(size_t)(k0 + kk) * 64 + c * 4];
        }
        __syncthreads();
#pragma unroll
        for (int rep = 0; rep < 2; rep++) {
            int idx = t + rep * 256; int dh = idx >> 3, cj = idx & 7;
            float sc = (p == 2) ? invV[h * 64 + dh] : 1.f;
            u16x8 o;
#pragma unroll
            for (int i = 0; i < 8; i++) o[i] = f2bf(sT[cj * 8 + i][dh] * sc);
            *(u16x8*)&wT[(size_t)(p * NC + h * 64 + dh) * DD + k0 + cj * 8] = o;
        }
    } else if (bid < 1152) {               // ---- pack W_O -> woT [768 d][1536 j] ----
        const int id2 = bid - 864;
        const int j0 = (id2 % 24) * 64, d0 = (id2 / 24) * 64;
#pragma unroll
        for (int rep = 0; rep < 4; rep++) {
            int idx = t + rep * 256; int jj = idx >> 4, c = idx & 15;
            *(float4*)&sT[jj][c * 4] = *(const float4*)&Wo[(size_t)(j0 + jj) * DD + d0 + c * 4];
        }
        __syncthreads();
#pragma unroll
        for (int rep = 0; rep < 2; rep++) {
            int idx = t + rep * 256; int dd = idx >> 3, cj = idx & 7;
            u16x8 o;
#pragma unroll
            for (int i = 0; i < 8; i++) o[i] = f2bf(sT[cj * 8 + i][dd]);
            *(u16x8*)&woT[(size_t)(d0 + dd) * NC + j0 + cj * 8] = o;
        }
    } else if (bid < 1280) {               // ---- pack gate weights -> wT rows [4608,4736) ----
        int g = bid - 1152;                // 0..127
        u16* dst = wT + (size_t)(NQKV + g) * DD;
        if (g < 48) {
            const float* src = ((g & 1) ? Wgk : Wgq) + (size_t)(g >> 1) * DD;
            for (int c = t; c < DD; c += 256) dst[c] = f2bf(src[c]);
        } else {
            for (int c = t; c < DD; c += 256) dst[c] = 0;
        }
    } else {                               // ---- pack bias ----
        int n = (bid - 1280) * 256 + t;
        if (n < NQKV) {
            int p = n / NC, rem = n % NC;
            biasp[n] = (p == 0) ? bq[rem] : (p == 1) ? bk[rem] : bv[rem];
        }
    }
}

// ---------------- qkv+gates MFMA GEMM: C[4096,4736] = xb @ wT^T ----------------
// v7: dbuf prefetch + XCD-chunked swizzle. Grid 1D 1184 blocks:
//   xcd = bid%8, idx = bid/8  ->  rb = xcd*148 + idx  (contiguous per XCD)
//   band = rb/296 (8 rows x 37 cols), col-major within band.
__global__ __launch_bounds__(256)
void qkv_gemm_kernel(const u16* __restrict__ xb, const u16* __restrict__ wT,
                     const float* __restrict__ biasp,
                     const float* __restrict__ bgq, const float* __restrict__ bgk,
                     u16* __restrict__ qo, u16* __restrict__ ko, u16* __restrict__ vto,
                     float* __restrict__ qgo, float* __restrict__ kgo) {
    const int bid = blockIdx.x;            // 0..1183 (= 8*148)
    const int rb = (bid & 7) * 148 + (bid >> 3);
    const int band = rb / 296, r2 = rb % 296;   // band: 8 rows x 37 cols
    const int bx = r2 >> 3, by = band * 8 + (r2 & 7);
    const int n0 = bx * 128, row0 = by * 128;

    const int t = threadIdx.x, w = t >> 6, l = t & 63, lr = l & 15, lq = l >> 4;
    const int wr = (w >> 1) * 64, wc = (w & 1) * 64;
    __shared__ u16 smem[2 * 16384];   // dbuf: [buf][sA 16KB | sB 16KB]; epi reuses 36KB

    const int src_row = l >> 3;            // 0..7 within 8-row chunk
    const int cbs = (l & 7) ^ src_row;     // swizzled source col-block
    const int swz = lr & 7;                // read-side swizzle

    auto stage = [&](int k0, int buf) {
        u16* sA = smem + buf * 16384;
        u16* sB = sA + 8192;
#pragma unroll
        for (int i = 0; i < 4; i++) {
            int ch = w * 4 + i;            // 16 chunks of 8 rows each
            int rowA = ch * 8 + src_row;
            async16(xb + (size_t)(row0 + rowA) * DD + k0 + cbs * 8, sA + ch * 512);
            async16(wT + (size_t)(n0 + rowA) * DD + k0 + cbs * 8, sB + ch * 512);
        }
    };

    stage(0, 0);
    int cur = 0;
    f32x4 acc[4][4] = {};
    for (int k0 = 0; k0 < DD; k0 += 64) {
        __syncthreads();                   // buf[cur] loads drained; prev reads done
        if (k0 + 64 < DD) stage(k0 + 64, cur ^ 1);
        const u16* sA = smem + cur * 16384;
        const u16* sB = sA + 8192;
#pragma unroll
        for (int s = 0; s < 2; s++) {
            const int j8 = ((s * 4 + lq) ^ swz) * 8;
            bf16x8 af[4], bf[4];
#pragma unroll
            for (int i = 0; i < 4; i++) {
                af[i] = *(const bf16x8*)&sA[(wr + i * 16 + lr) * 64 + j8];
                bf[i] = *(const bf16x8*)&sB[(wc + i * 16 + lr) * 64 + j8];
            }
#pragma unroll
            for (int mt = 0; mt < 4; mt++)
#pragma unroll
                for (int nt = 0; nt < 4; nt++)
                    acc[mt][nt] = __builtin_amdgcn_mfma_f32_16x16x32_bf16(
                        af[mt], bf[nt], acc[mt][nt], 0, 0, 0);
        }
        cur ^= 1;
    }
    __syncthreads();                       // frag reads done before LDS reuse

    const int p = n0 / NC;                 // 0..3 (3 = gate block)
    const int b = row0 >> 10, s0 = row0 & (SS - 1);

    if (p == 3) {                          // gates: cols j = nt*16+lr < 48
        if (wc == 0) {
#pragma unroll
            for (int nt = 0; nt < 3; nt++) {
                int j = nt * 16 + lr, hh = j >> 1;
                float bias = (j & 1) ? bgk[hh] : bgq[hh];
                float* dst = (j & 1) ? kgo : qgo;
#pragma unroll
                for (int mt = 0; mt < 4; mt++)
#pragma unroll
                    for (int r = 0; r < 4; r++)
                        dst[((size_t)b * HH + hh) * SS + s0 + wr + mt * 16 + lq * 4 + r] =
                            acc[mt][nt][r] + bias;
            }
        }
        return;
    }

    const int cq = n0 + wc, srow = s0 + wr;
    u16* tw = smem + w * 4608;             // per-wave 64 x 72 region
    float bb[4];
#pragma unroll
    for (int nt = 0; nt < 4; nt++) bb[nt] = biasp[cq + nt * 16 + lr];

    if (p < 2) {                           // q or k: layout [s][dh]
        const float sc = (p == 0) ? 0.125f : 1.f;   // fold 1/sqrt(64) into q
#pragma unroll
        for (int mt = 0; mt < 4; mt++)
#pragma unroll
            for (int nt = 0; nt < 4; nt++)
#pragma unroll
                for (int r = 0; r < 4; r++)
                    tw[(mt * 16 + lq * 4 + r) * 72 + nt * 16 + lr] =
                        f2bf((acc[mt][nt][r] + bb[nt]) * sc);
        const int h = (cq - p * NC) >> 6;
        u16* dst = (p == 0 ? qo : ko) + ((size_t)(b * HH + h) * SS + srow) * 64;
#pragma unroll
        for (int c = 0; c < 8; c++)
            *(u16x8*)&dst[(size_t)l * 64 + c * 8] = *(const u16x8*)&tw[l * 72 + c * 8];
    } else {                               // v: transpose to [dh][s]
#pragma unroll
        for (int mt = 0; mt < 4; mt++)
#pragma unroll
            for (int nt = 0; nt < 4; nt++)
#pragma unroll
                for (int r = 0; r < 4; r++)
                    tw[(nt * 16 + lr) * 72 + mt * 16 + lq * 4 + r] =
                        f2bf(acc[mt][nt][r] + bb[nt]);
        const int h = (cq - 2 * NC) >> 6;
        u16* dst = vto + ((size_t)(b * HH + h) * 64 + l) * SS + srow;
#pragma unroll
        for (int c = 0; c < 8; c++)
            *(u16x8*)&dst[c * 8] = *(const u16x8*)&tw[l * 72 + c * 8];
    }
}

// ---------------- MFMA flash attention, balanced pairs + dbuf K/V staging ----------------
// v11 body (reverted from v12): 1D grid 768, XCD-aware remap (all 8 pr-blocks
// of a (b,h) on one XCD; 12 bh x 256KB = 3MB fits 4MB L2). K AND V staged in
// LDS (dropping V staging regressed: per-lane V loads = 16 lines/instr).
__global__ __launch_bounds__(256)
void attn_kernel(const u16* __restrict__ qb, const u16* __restrict__ kb,
                 const u16* __restrict__ vtb, const float* __restrict__ qg,
                 const float* __restrict__ kg, const float* __restrict__ invO,
                 u16* __restrict__ z) {
    const int bid = blockIdx.x;            // 0..767
    const int xcd = bid & 7, idx = bid >> 3;
    const int hb = xcd * 12 + (idx >> 3);  // 0..95
    const int pr = idx & 7;
    const int h = hb % HH, b = hb / HH;
    const int t = threadIdx.x, w = t >> 6, l = t & 63, lr = l & 15, lq = l >> 4;

    __shared__ u16 sK[2][64 * 64], sVT[2][64 * 64];
    __shared__ u16 sP[4][16 * 72];
    u16* tP = sP[w];

    const size_t bh = (size_t)(b * HH + h);
    const u16* Kb = kb + bh * SS * 64;
    const u16* Vt = vtb + bh * 64 * SS;
    const float* kgb = kg + bh * SS;

    const int src_row = l >> 3;
    const int cbs = (l & 7) ^ src_row;
    const int swz = lr & 7;

    auto stage = [&](int kt, int buf) {
#pragma unroll
        for (int i = 0; i < 2; i++) {
            int kc = w * 2 + i;            // 8 chunks x 8 rows; LDS base wave-uniform
            int row = kc * 8 + src_row;
            async16(Kb + ((size_t)(kt * 64 + row)) * 64 + cbs * 8, sK[buf] + kc * 512);
            async16(Vt + (size_t)row * SS + kt * 64 + cbs * 8, sVT[buf] + kc * 512);
        }
    };

    stage(0, 0);
    int cur = 0;
#pragma unroll
    for (int sub = 0; sub < 2; sub++) {
        const int QT = sub ? (15 - pr) : pr;
        const int q0 = QT * 64 + w * 16;   // wave's first q row
        const u16* Qw = qb + (bh * SS + q0) * 64;
        bf16x8 aq0 = *(const bf16x8*)(Qw + (size_t)lr * 64 + lq * 8);
        bf16x8 aq1 = *(const bf16x8*)(Qw + (size_t)lr * 64 + 32 + lq * 8);
        float qgr[4];
#pragma unroll
        for (int r = 0; r < 4; r++) qgr[r] = qg[bh * SS + q0 + lq * 4 + r];

        f32x4 o[4] = {};
        float lacc[4] = {};

        for (int kt = 0; kt <= QT; kt++) {
            __syncthreads();               // buf[cur] loads drained; prev reads done
            if (kt < QT) stage(kt + 1, cur ^ 1);
            else if (sub == 0) stage(0, cur ^ 1);
            const u16* K_ = sK[cur];
            const u16* V_ = sVT[cur];

            // kg values straight from global (L2-resident)
            float kgv[4];
#pragma unroll
            for (int nt = 0; nt < 4; nt++) kgv[nt] = kgb[kt * 64 + nt * 16 + lr];

            // S = Q K^T (q pre-scaled by 1/sqrt(64))
            f32x4 sf[4] = {};
#pragma unroll
            for (int s = 0; s < 2; s++) {
                const int j8 = ((s * 4 + lq) ^ swz) * 8;
                const bf16x8 aqs = s ? aq1 : aq0;
#pragma unroll
                for (int nt = 0; nt < 4; nt++) {
                    bf16x8 bk = *(const bf16x8*)&K_[(nt * 16 + lr) * 64 + j8];
                    sf[nt] = __builtin_amdgcn_mfma_f32_16x16x32_bf16(aqs, bk, sf[nt], 0, 0, 0);
                }
            }
            if (kt == QT) {                // diagonal tile: causal mask
#pragma unroll
                for (int nt = 0; nt < 4; nt++)
#pragma unroll
                    for (int r = 0; r < 4; r++)
                        if (nt * 16 + lr > w * 16 + lq * 4 + r) sf[nt][r] = -INFINITY;
            }

            // p = exp(s); l += p; P_gated -> wave-local LDS (bf16)
#pragma unroll
            for (int nt = 0; nt < 4; nt++)
#pragma unroll
                for (int r = 0; r < 4; r++) {
                    float pv = __expf(sf[nt][r]);
                    lacc[r] += pv;
                    float g = fminf(fmaxf(qgr[r] * kgv[nt], 0.f), 1.f);
                    tP[(lq * 4 + r) * 72 + nt * 16 + lr] = f2bf(pv * g);
                }

            // O += P V (wave-local tP: no barrier)
#pragma unroll
            for (int c = 0; c < 2; c++) {
                bf16x8 ap = *(const bf16x8*)&tP[lr * 72 + c * 32 + lq * 8];
                const int j8 = ((c * 4 + lq) ^ swz) * 8;
#pragma unroll
                for (int dt = 0; dt < 4; dt++) {
                    bf16x8 bv = *(const bf16x8*)&V_[(dt * 16 + lr) * 64 + j8];
                    o[dt] = __builtin_amdgcn_mfma_f32_16x16x32_bf16(ap, bv, o[dt], 0, 0, 0);
                }
            }
            cur ^= 1;
        }

        // final l reduction across the 16 lanes sharing each q-row
#pragma unroll
        for (int r = 0; r < 4; r++) {
            float v = lacc[r];
            v += __shfl_xor(v, 1);
            v += __shfl_xor(v, 2);
            v += __shfl_xor(v, 4);
            v += __shfl_xor(v, 8);
            lacc[r] = __builtin_amdgcn_rcpf(v);
        }

        // epilogue: z = (o/l)*invO -> bf16 [B,S,1536]
        const int col0 = h * 64;
#pragma unroll
        for (int dt = 0; dt < 4; dt++) {
            float io = invO[col0 + dt * 16 + lr];
#pragma unroll
            for (int r = 0; r < 4; r++) {
                float val = o[dt][r] * lacc[r] * io;
                z[((size_t)b * SS + q0 + lq * 4 + r) * NC + col0 + dt * 16 + lr] = f2bf(val);
            }
        }
    }
}

// ---------------- out MFMA GEMM: out[4096,768] = z[4096,1536] @ woT[d][j]^T ----------------
// v13: 128x96 tiles, grid 32x8 = 256 blocks = exactly 1/CU (zero tail).
// Per wave: 64x48 output (acc 4x3), 24 MFMA + 7 ds_read_b128 per K-step.
// XCD-chunked: xcd gets 4 M-panels x 8 N-tiles; A 1.5MB + woT 2.4MB < 4MB L2.
// LDS: dbuf 2 x (128+96)x64x2B = 57.3KB.
__global__ __launch_bounds__(256)
void out_gemm_kernel(const u16* __restrict__ zb, const u16* __restrict__ woT,
                     float* __restrict__ out) {
    const int bid = blockIdx.x;            // 0..255 (= 8*32)
    const int xcd = bid & 7, idx = bid >> 3;        // idx 0..31
    const int by = xcd * 4 + (idx >> 3);            // M-tile 0..31
    const int bx = idx & 7;                         // N-tile 0..7
    const int n0 = bx * 96, row0 = by * 128;

    const int t = threadIdx.x, w = t >> 6, l = t & 63, lr = l & 15, lq = l >> 4;
    const int wr = (w >> 1) * 64, wc = (w & 1) * 48;
    __shared__ u16 smem[2 * 14336];   // [buf][A 128x64 | B 96x64]

    const int src_row = l >> 3;
    const int cbs = (l & 7) ^ src_row;
    const int swz = lr & 7;

    auto stage = [&](int k0, int buf) {
        u16* sA = smem + buf * 14336;
        u16* sB = sA + 8192;
#pragma unroll
        for (int i = 0; i < 4; i++) {      // A: 16 chunks of 8 rows
            int ch = w * 4 + i;
            int row = ch * 8 + src_row;
            async16(zb + (size_t)(row0 + row) * NC + k0 + cbs * 8, sA + ch * 512);
        }
#pragma unroll
        for (int i = 0; i < 3; i++) {      // B: 12 chunks of 8 rows
            int ch = w * 3 + i;
            int row = ch * 8 + src_row;
            async16(woT + (size_t)(n0 + row) * NC + k0 + cbs * 8, sB + ch * 512);
        }
    };

    stage(0, 0);
    int cur = 0;
    f32x4 acc[4][3] = {};
    for (int k0 = 0; k0 < NC; k0 += 64) {
        __syncthreads();
        if (k0 + 64 < NC) stage(k0 + 64, cur ^ 1);
        const u16* sA = smem + cur * 14336;
        const u16* sB = sA + 8192;
#pragma unroll
        for (int s = 0; s < 2; s++) {
            const int j8 = ((s * 4 + lq) ^ swz) * 8;
            bf16x8 af[4], bf[3];
#pragma unroll
            for (int i = 0; i < 4; i++)
                af[i] = *(const bf16x8*)&sA[(wr + i * 16 + lr) * 64 + j8];
#pragma unroll
            for (int i = 0; i < 3; i++)
                bf[i] = *(const bf16x8*)&sB[(wc + i * 16 + lr) * 64 + j8];
#pragma unroll
            for (int mt = 0; mt < 4; mt++)
#pragma unroll
                for (int nt = 0; nt < 3; nt++)
                    acc[mt][nt] = __builtin_amdgcn_mfma_f32_16x16x32_bf16(
                        af[mt], bf[nt], acc[mt][nt], 0, 0, 0);
        }
        cur ^= 1;
    }
#pragma unroll
    for (int mt = 0; mt < 4; mt++)
#pragma unroll
        for (int nt = 0; nt < 3; nt++)
#pragma unroll
            for (int r = 0; r < 4; r++)
                out[(size_t)(row0 + wr + mt * 16 + lq * 4 + r) * DD + n0 + wc + nt * 16 + lr] =
                    acc[mt][nt][r];
}

}  // namespace

extern "C" void kernel_launch(void* const* d_in, const int* in_sizes, int n_in,
                              void* d_out, int out_size, void* d_ws, size_t ws_size,
                              hipStream_t stream) {
    const float* x   = (const float*)d_in[0];
    const float* W_Q = (const float*)d_in[1];
    const float* W_K = (const float*)d_in[2];
    const float* W_V = (const float*)d_in[3];
    const float* W_O = (const float*)d_in[4];
    const float* b_Q = (const float*)d_in[5];
    const float* b_K = (const float*)d_in[6];
    const float* b_V = (const float*)d_in[7];
    const float* Wgq = (const float*)d_in[8];
    const float* Wgk = (const float*)d_in[9];
    const float* bgq = (const float*)d_in[10];
    const float* bgk = (const float*)d_in[11];
    float* out = (float*)d_out;

    char* wsb = (char*)d_ws;
    auto alloc = [&](size_t bytes) -> char* {
        char* p = wsb;
        wsb += (bytes + 255) & ~(size_t)255;
        return p;
    };
    float* invV  = (float*)alloc((size_t)NC * 4);
    float* invO  = (float*)alloc((size_t)NC * 4);
    float* biasp = (float*)alloc((size_t)NQKV * 4);
    float* qg    = (float*)alloc((size_t)RR * HH * 4);
    float* kg    = (float*)alloc((size_t)RR * HH * 4);
    u16* xb      = (u16*)alloc((size_t)RR * DD * 2);
    u16* wT      = (u16*)alloc((size_t)NTOT * DD * 2);
    u16* woT     = (u16*)alloc((size_t)DD * NC * 2);
    u16* qb      = (u16*)alloc((size_t)RR * 64 * HH * 2);
    u16* kb      = (u16*)alloc((size_t)RR * 64 * HH * 2);
    u16* vtb     = (u16*)alloc((size_t)RR * 64 * HH * 2);
    u16* zb      = (u16*)alloc((size_t)RR * NC * 2);

    prep_a_kernel<<<NC + RR * DD / 4 / 256, 256, 0, stream>>>(
        W_V, W_O, invV, invO, x, xb);
    prep_b_kernel<<<1298, 256, 0, stream>>>(
        W_Q, W_K, W_V, invV, wT, W_O, woT, Wgq, Wgk, b_Q, b_K, b_V, biasp);
    qkv_gemm_kernel<<<NTOT / 128 * (RR / 128), 256, 0, stream>>>(
        xb, wT, biasp, bgq, bgk, qb, kb, vtb, qg, kg);
    attn_kernel<<<768, 256, 0, stream>>>(
        qb, kb, vtb, qg, kg, invO, zb);
    out_gemm_kernel<<<256, 256, 0, stream>>>(zb, woT, out);
}

// Round 9
// 199.350 us; speedup vs baseline: 1.1485x; 1.0400x over previous
//
#include <hip/hip_runtime.h>
#include <math.h>

// ModifiedAttention bf16-MFMA pipeline v14: B=4,S=1024,D=768,H=24,DH=64,DG=1
//  - out_gemm: NEW 64x96 tiles, grid 512 = exactly 2 blocks/CU launch-wise and
//    4 blocks/CU resident (LDS 40KB dbuf). Fixes both prior failure modes:
//    64x64 = 8MFMA:8read per step (poor amortization); 128x96 = 1/CU (drain
//    exposed, measured neutral). 64x96 = 12MFMA:5read + 4-deep residency.
//    Same 2-phase structure + swizzles; bit-identical numerics.
//  - attn: v11 (K+V LDS-staged, XCD remap: 8 pr-blocks of a (b,h) per XCD).
//    V-direct (R7) regressed: per-lane V loads touch 16 lines/instr.
//  - qkv: v7 2-phase dbuf + XCD swizzle (structure ceiling; R3/R4 regressed).
//  - preps fused 6->2 (R6, -10us). Gates folded into qkv; max-free softmax.
//  Ledger (measured/derived): qkv 50 | attn ~40 | out ~28->target 17 | preps 9.

namespace {

typedef short bf16x8 __attribute__((ext_vector_type(8)));
typedef float f32x4 __attribute__((ext_vector_type(4)));
typedef unsigned short u16;
typedef u16 u16x8 __attribute__((ext_vector_type(8)));
typedef unsigned int u32;

constexpr int BB = 4, SS = 1024, DD = 768, HH = 24;
constexpr int RR = BB * SS;     // 4096
constexpr int NC = HH * 64;     // 1536
constexpr int NQKV = 3 * NC;    // 4608
constexpr int NTOT = NQKV + 128; // + gate block

__device__ inline u16 f2bf(float f) {   // RNE fp32 -> bf16
    u32 u = __float_as_uint(f);
    u += 0x7FFFu + ((u >> 16) & 1u);
    return (u16)(u >> 16);
}

// async global->LDS, 16B/lane; LDS base MUST be wave-uniform (HW scatters lane*16)
__device__ __forceinline__ void async16(const void* g, const void* lds) {
    __builtin_amdgcn_global_load_lds(
        (const __attribute__((address_space(1))) u32*)(unsigned long long)(size_t)g,
        (__attribute__((address_space(3))) u32*)(u32)(size_t)lds, 16, 0, 0);
}

// ---------------- fused prep A: norms (blocks [0,1536)) + x2bf ([1536,4608)) ----------------
__global__ __launch_bounds__(256)
void prep_a_kernel(const float* __restrict__ Wv, const float* __restrict__ Wo,
                   float* __restrict__ invV, float* __restrict__ invO,
                   const float* __restrict__ x, u16* __restrict__ xb) {
    const int bid = blockIdx.x;
    if (bid < NC) {                        // ---- norms ----
        int j = bid;                       // (h,dh) flat, 1536
        int h = j >> 6, dh = j & 63;
        __shared__ float sv[256], so[256];
        float av = 0.f, ao = 0.f;
        for (int d = threadIdx.x; d < DD; d += 256) {
            float a = Wv[(h * DD + d) * 64 + dh];    // W_V[h,d,dh], norm over d
            av += a * a;
            float b = Wo[(size_t)j * DD + d];        // W_O[h,dh,d], norm over d
            ao += b * b;
        }
        sv[threadIdx.x] = av; so[threadIdx.x] = ao;
        __syncthreads();
        for (int s = 128; s > 0; s >>= 1) {
            if (threadIdx.x < s) {
                sv[threadIdx.x] += sv[threadIdx.x + s];
                so[threadIdx.x] += so[threadIdx.x + s];
            }
            __syncthreads();
        }
        if (threadIdx.x == 0) {
            invV[j] = 1.f / fmaxf(sqrtf(sv[0]), 1e-12f);
            invO[j] = 1.f / fmaxf(sqrtf(so[0]), 1e-12f);
        }
    } else {                               // ---- x -> bf16 ----
        int idx = (bid - NC) * 256 + threadIdx.x;   // RR*DD/4 float4s
        float4 v = ((const float4*)x)[idx];
        ushort4 o;
        o.x = f2bf(v.x); o.y = f2bf(v.y); o.z = f2bf(v.z); o.w = f2bf(v.w);
        ((ushort4*)xb)[idx] = o;
    }
}

// ---------------- fused prep B: pack_wqkv [0,864) | pack_wo [864,1152) |
//                  pack_gates [1152,1280) | pack_bias [1280,1298) ----------------
__global__ __launch_bounds__(256)
void prep_b_kernel(const float* __restrict__ Wq, const float* __restrict__ Wk,
                   const float* __restrict__ Wv, const float* __restrict__ invV,
                   u16* __restrict__ wT,
                   const float* __restrict__ Wo, u16* __restrict__ woT,
                   const float* __restrict__ Wgq, const float* __restrict__ Wgk,
                   const float* __restrict__ bq, const float* __restrict__ bk,
                   const float* __restrict__ bv, float* __restrict__ biasp) {
    const int bid = blockIdx.x;
    const int t = threadIdx.x;
    __shared__ float sT[64][68];

    if (bid < 864) {                       // ---- pack W_{Q,K,V} -> wT rows [0,4608) ----
        const int bx = bid % 12, h = (bid / 12) % 24, p = bid / 288;
        const int k0 = bx * 64;
        const float* W = (p == 0 ? Wq : p == 1 ? Wk : Wv) + (size_t)h * DD * 64;
#pragma unroll
        for (int rep = 0; rep < 4; rep++) {
            int idx = t + rep * 256; int kk = idx >> 4, c = idx & 15;
            *(float4*)&sT[kk][c * 4] = *(const float4*)&W[(size_t)(k0 + kk) * 64 + c * 4];
        }
        __syncthreads();
#pragma unroll
        for (int rep = 0; rep < 2; rep++) {
            int idx = t + rep * 256; int dh = idx >> 3, cj = idx & 7;
            float sc = (p == 2) ? invV[h * 64 + dh] : 1.f;
            u16x8 o;
#pragma unroll
            for (int i = 0; i < 8; i++) o[i] = f2bf(sT[cj * 8 + i][dh] * sc);
            *(u16x8*)&wT[(size_t)(p * NC + h * 64 + dh) * DD + k0 + cj * 8] = o;
        }
    } else if (bid < 1152) {               // ---- pack W_O -> woT [768 d][1536 j] ----
        const int id2 = bid - 864;
        const int j0 = (id2 % 24) * 64, d0 = (id2 / 24) * 64;
#pragma unroll
        for (int rep = 0; rep < 4; rep++) {
            int idx = t + rep * 256; int jj = idx >> 4, c = idx & 15;
            *(float4*)&sT[jj][c * 4] = *(const float4*)&Wo[(size_t)(j0 + jj) * DD + d0 + c * 4];
        }
        __syncthreads();
#pragma unroll
        for (int rep = 0; rep < 2; rep++) {
            int idx = t + rep * 256; int dd = idx >> 3, cj = idx & 7;
            u16x8 o;
#pragma unroll
            for (int i = 0; i < 8; i++) o[i] = f2bf(sT[cj * 8 + i][dd]);
            *(u16x8*)&woT[(size_t)(d0 + dd) * NC + j0 + cj * 8] = o;
        }
    } else if (bid < 1280) {               // ---- pack gate weights -> wT rows [4608,4736) ----
        int g = bid - 1152;                // 0..127
        u16* dst = wT + (size_t)(NQKV + g) * DD;
        if (g < 48) {
            const float* src = ((g & 1) ? Wgk : Wgq) + (size_t)(g >> 1) * DD;
            for (int c = t; c < DD; c += 256) dst[c] = f2bf(src[c]);
        } else {
            for (int c = t; c < DD; c += 256) dst[c] = 0;
        }
    } else {                               // ---- pack bias ----
        int n = (bid - 1280) * 256 + t;
        if (n < NQKV) {
            int p = n / NC, rem = n % NC;
            biasp[n] = (p == 0) ? bq[rem] : (p == 1) ? bk[rem] : bv[rem];
        }
    }
}

// ---------------- qkv+gates MFMA GEMM: C[4096,4736] = xb @ wT^T ----------------
// v7: dbuf prefetch + XCD-chunked swizzle. Grid 1D 1184 blocks:
//   xcd = bid%8, idx = bid/8  ->  rb = xcd*148 + idx  (contiguous per XCD)
//   band = rb/296 (8 rows x 37 cols), col-major within band.
__global__ __launch_bounds__(256)
void qkv_gemm_kernel(const u16* __restrict__ xb, const u16* __restrict__ wT,
                     const float* __restrict__ biasp,
                     const float* __restrict__ bgq, const float* __restrict__ bgk,
                     u16* __restrict__ qo, u16* __restrict__ ko, u16* __restrict__ vto,
                     float* __restrict__ qgo, float* __restrict__ kgo) {
    const int bid = blockIdx.x;            // 0..1183 (= 8*148)
    const int rb = (bid & 7) * 148 + (bid >> 3);
    const int band = rb / 296, r2 = rb % 296;   // band: 8 rows x 37 cols
    const int bx = r2 >> 3, by = band * 8 + (r2 & 7);
    const int n0 = bx * 128, row0 = by * 128;

    const int t = threadIdx.x, w = t >> 6, l = t & 63, lr = l & 15, lq = l >> 4;
    const int wr = (w >> 1) * 64, wc = (w & 1) * 64;
    __shared__ u16 smem[2 * 16384];   // dbuf: [buf][sA 16KB | sB 16KB]; epi reuses 36KB

    const int src_row = l >> 3;            // 0..7 within 8-row chunk
    const int cbs = (l & 7) ^ src_row;     // swizzled source col-block
    const int swz = lr & 7;                // read-side swizzle

    auto stage = [&](int k0, int buf) {
        u16* sA = smem + buf * 16384;
        u16* sB = sA + 8192;
#pragma unroll
        for (int i = 0; i < 4; i++) {
            int ch = w * 4 + i;            // 16 chunks of 8 rows each
            int rowA = ch * 8 + src_row;
            async16(xb + (size_t)(row0 + rowA) * DD + k0 + cbs * 8, sA + ch * 512);
            async16(wT + (size_t)(n0 + rowA) * DD + k0 + cbs * 8, sB + ch * 512);
        }
    };

    stage(0, 0);
    int cur = 0;
    f32x4 acc[4][4] = {};
    for (int k0 = 0; k0 < DD; k0 += 64) {
        __syncthreads();                   // buf[cur] loads drained; prev reads done
        if (k0 + 64 < DD) stage(k0 + 64, cur ^ 1);
        const u16* sA = smem + cur * 16384;
        const u16* sB = sA + 8192;
#pragma unroll
        for (int s = 0; s < 2; s++) {
            const int j8 = ((s * 4 + lq) ^ swz) * 8;
            bf16x8 af[4], bf[4];
#pragma unroll
            for (int i = 0; i < 4; i++) {
                af[i] = *(const bf16x8*)&sA[(wr + i * 16 + lr) * 64 + j8];
                bf[i] = *(const bf16x8*)&sB[(wc + i * 16 + lr) * 64 + j8];
            }
#pragma unroll
            for (int mt = 0; mt < 4; mt++)
#pragma unroll
                for (int nt = 0; nt < 4; nt++)
                    acc[mt][nt] = __builtin_amdgcn_mfma_f32_16x16x32_bf16(
                        af[mt], bf[nt], acc[mt][nt], 0, 0, 0);
        }
        cur ^= 1;
    }
    __syncthreads();                       // frag reads done before LDS reuse

    const int p = n0 / NC;                 // 0..3 (3 = gate block)
    const int b = row0 >> 10, s0 = row0 & (SS - 1);

    if (p == 3) {                          // gates: cols j = nt*16+lr < 48
        if (wc == 0) {
#pragma unroll
            for (int nt = 0; nt < 3; nt++) {
                int j = nt * 16 + lr, hh = j >> 1;
                float bias = (j & 1) ? bgk[hh] : bgq[hh];
                float* dst = (j & 1) ? kgo : qgo;
#pragma unroll
                for (int mt = 0; mt < 4; mt++)
#pragma unroll
                    for (int r = 0; r < 4; r++)
                        dst[((size_t)b * HH + hh) * SS + s0 + wr + mt * 16 + lq * 4 + r] =
                            acc[mt][nt][r] + bias;
            }
        }
        return;
    }

    const int cq = n0 + wc, srow = s0 + wr;
    u16* tw = smem + w * 4608;             // per-wave 64 x 72 region
    float bb[4];
#pragma unroll
    for (int nt = 0; nt < 4; nt++) bb[nt] = biasp[cq + nt * 16 + lr];

    if (p < 2) {                           // q or k: layout [s][dh]
        const float sc = (p == 0) ? 0.125f : 1.f;   // fold 1/sqrt(64) into q
#pragma unroll
        for (int mt = 0; mt < 4; mt++)
#pragma unroll
            for (int nt = 0; nt < 4; nt++)
#pragma unroll
                for (int r = 0; r < 4; r++)
                    tw[(mt * 16 + lq * 4 + r) * 72 + nt * 16 + lr] =
                        f2bf((acc[mt][nt][r] + bb[nt]) * sc);
        const int h = (cq - p * NC) >> 6;
        u16* dst = (p == 0 ? qo : ko) + ((size_t)(b * HH + h) * SS + srow) * 64;
#pragma unroll
        for (int c = 0; c < 8; c++)
            *(u16x8*)&dst[(size_t)l * 64 + c * 8] = *(const u16x8*)&tw[l * 72 + c * 8];
    } else {                               // v: transpose to [dh][s]
#pragma unroll
        for (int mt = 0; mt < 4; mt++)
#pragma unroll
            for (int nt = 0; nt < 4; nt++)
#pragma unroll
                for (int r = 0; r < 4; r++)
                    tw[(nt * 16 + lr) * 72 + mt * 16 + lq * 4 + r] =
                        f2bf(acc[mt][nt][r] + bb[nt]);
        const int h = (cq - 2 * NC) >> 6;
        u16* dst = vto + ((size_t)(b * HH + h) * 64 + l) * SS + srow;
#pragma unroll
        for (int c = 0; c < 8; c++)
            *(u16x8*)&dst[c * 8] = *(const u16x8*)&tw[l * 72 + c * 8];
    }
}

// ---------------- MFMA flash attention, balanced pairs + dbuf K/V staging ----------------
// v11: 1D grid 768, XCD-aware remap (all 8 pr-blocks of a (b,h) on one XCD;
// 12 bh x 256KB = 3MB fits 4MB L2). K AND V staged in LDS.
__global__ __launch_bounds__(256)
void attn_kernel(const u16* __restrict__ qb, const u16* __restrict__ kb,
                 const u16* __restrict__ vtb, const float* __restrict__ qg,
                 const float* __restrict__ kg, const float* __restrict__ invO,
                 u16* __restrict__ z) {
    const int bid = blockIdx.x;            // 0..767
    const int xcd = bid & 7, idx = bid >> 3;
    const int hb = xcd * 12 + (idx >> 3);  // 0..95
    const int pr = idx & 7;
    const int h = hb % HH, b = hb / HH;
    const int t = threadIdx.x, w = t >> 6, l = t & 63, lr = l & 15, lq = l >> 4;

    __shared__ u16 sK[2][64 * 64], sVT[2][64 * 64];
    __shared__ u16 sP[4][16 * 72];
    u16* tP = sP[w];

    const size_t bh = (size_t)(b * HH + h);
    const u16* Kb = kb + bh * SS * 64;
    const u16* Vt = vtb + bh * 64 * SS;
    const float* kgb = kg + bh * SS;

    const int src_row = l >> 3;
    const int cbs = (l & 7) ^ src_row;
    const int swz = lr & 7;

    auto stage = [&](int kt, int buf) {
#pragma unroll
        for (int i = 0; i < 2; i++) {
            int kc = w * 2 + i;            // 8 chunks x 8 rows; LDS base wave-uniform
            int row = kc * 8 + src_row;
            async16(Kb + ((size_t)(kt * 64 + row)) * 64 + cbs * 8, sK[buf] + kc * 512);
            async16(Vt + (size_t)row * SS + kt * 64 + cbs * 8, sVT[buf] + kc * 512);
        }
    };

    stage(0, 0);
    int cur = 0;
#pragma unroll
    for (int sub = 0; sub < 2; sub++) {
        const int QT = sub ? (15 - pr) : pr;
        const int q0 = QT * 64 + w * 16;   // wave's first q row
        const u16* Qw = qb + (bh * SS + q0) * 64;
        bf16x8 aq0 = *(const bf16x8*)(Qw + (size_t)lr * 64 + lq * 8);
        bf16x8 aq1 = *(const bf16x8*)(Qw + (size_t)lr * 64 + 32 + lq * 8);
        float qgr[4];
#pragma unroll
        for (int r = 0; r < 4; r++) qgr[r] = qg[bh * SS + q0 + lq * 4 + r];

        f32x4 o[4] = {};
        float lacc[4] = {};

        for (int kt = 0; kt <= QT; kt++) {
            __syncthreads();               // buf[cur] loads drained; prev reads done
            if (kt < QT) stage(kt + 1, cur ^ 1);
            else if (sub == 0) stage(0, cur ^ 1);
            const u16* K_ = sK[cur];
            const u16* V_ = sVT[cur];

            // kg values straight from global (L2-resident)
            float kgv[4];
#pragma unroll
            for (int nt = 0; nt < 4; nt++) kgv[nt] = kgb[kt * 64 + nt * 16 + lr];

            // S = Q K^T (q pre-scaled by 1/sqrt(64))
            f32x4 sf[4] = {};
#pragma unroll
            for (int s = 0; s < 2; s++) {
                const int j8 = ((s * 4 + lq) ^ swz) * 8;
                const bf16x8 aqs = s ? aq1 : aq0;
#pragma unroll
                for (int nt = 0; nt < 4; nt++) {
                    bf16x8 bk = *(const bf16x8*)&K_[(nt * 16 + lr) * 64 + j8];
                    sf[nt] = __builtin_amdgcn_mfma_f32_16x16x32_bf16(aqs, bk, sf[nt], 0, 0, 0);
                }
            }
            if (kt == QT) {                // diagonal tile: causal mask
#pragma unroll
                for (int nt = 0; nt < 4; nt++)
#pragma unroll
                    for (int r = 0; r < 4; r++)
                        if (nt * 16 + lr > w * 16 + lq * 4 + r) sf[nt][r] = -INFINITY;
            }

            // p = exp(s); l += p; P_gated -> wave-local LDS (bf16)
#pragma unroll
            for (int nt = 0; nt < 4; nt++)
#pragma unroll
                for (int r = 0; r < 4; r++) {
                    float pv = __expf(sf[nt][r]);
                    lacc[r] += pv;
                    float g = fminf(fmaxf(qgr[r] * kgv[nt], 0.f), 1.f);
                    tP[(lq * 4 + r) * 72 + nt * 16 + lr] = f2bf(pv * g);
                }

            // O += P V (wave-local tP: no barrier)
#pragma unroll
            for (int c = 0; c < 2; c++) {
                bf16x8 ap = *(const bf16x8*)&tP[lr * 72 + c * 32 + lq * 8];
                const int j8 = ((c * 4 + lq) ^ swz) * 8;
#pragma unroll
                for (int dt = 0; dt < 4; dt++) {
                    bf16x8 bv = *(const bf16x8*)&V_[(dt * 16 + lr) * 64 + j8];
                    o[dt] = __builtin_amdgcn_mfma_f32_16x16x32_bf16(ap, bv, o[dt], 0, 0, 0);
                }
            }
            cur ^= 1;
        }

        // final l reduction across the 16 lanes sharing each q-row
#pragma unroll
        for (int r = 0; r < 4; r++) {
            float v = lacc[r];
            v += __shfl_xor(v, 1);
            v += __shfl_xor(v, 2);
            v += __shfl_xor(v, 4);
            v += __shfl_xor(v, 8);
            lacc[r] = __builtin_amdgcn_rcpf(v);
        }

        // epilogue: z = (o/l)*invO -> bf16 [B,S,1536]
        const int col0 = h * 64;
#pragma unroll
        for (int dt = 0; dt < 4; dt++) {
            float io = invO[col0 + dt * 16 + lr];
#pragma unroll
            for (int r = 0; r < 4; r++) {
                float val = o[dt][r] * lacc[r] * io;
                z[((size_t)b * SS + q0 + lq * 4 + r) * NC + col0 + dt * 16 + lr] = f2bf(val);
            }
        }
    }
}

// ---------------- out MFMA GEMM: out[4096,768] = z[4096,1536] @ woT[d][j]^T ----------------
// v14: 64x96 tiles, grid 512 = 8 XCD x 64 (8 M-panels x 8 N-tiles per XCD;
// A 1.5MB + woT 2.4MB = 3.9MB fits 4MB L2). Per wave 32x48 (acc 2x3),
// 12 MFMA + 5 ds_read_b128 per K-step; LDS dbuf 40KB -> 4 blocks/CU resident.
__global__ __launch_bounds__(256)
void out_gemm_kernel(const u16* __restrict__ zb, const u16* __restrict__ woT,
                     float* __restrict__ out) {
    const int bid = blockIdx.x;            // 0..511 (= 8*64)
    const int xcd = bid & 7, idx = bid >> 3;        // idx 0..63
    const int by = xcd * 8 + (idx >> 3);            // M-tile 0..63
    const int bx = idx & 7;                         // N-tile 0..7
    const int n0 = bx * 96, row0 = by * 64;

    const int t = threadIdx.x, w = t >> 6, l = t & 63, lr = l & 15, lq = l >> 4;
    const int wr = (w >> 1) * 32, wc = (w & 1) * 48;
    __shared__ u16 smem[2 * 10240];   // [buf][A 64x64 | B 96x64] = 2 x 20KB

    const int src_row = l >> 3;
    const int cbs = (l & 7) ^ src_row;
    const int swz = lr & 7;

    auto stage = [&](int k0, int buf) {
        u16* sA = smem + buf * 10240;
        u16* sB = sA + 4096;
#pragma unroll
        for (int i = 0; i < 2; i++) {      // A: 8 chunks of 8 rows
            int ch = w * 2 + i;
            int row = ch * 8 + src_row;
            async16(zb + (size_t)(row0 + row) * NC + k0 + cbs * 8, sA + ch * 512);
        }
#pragma unroll
        for (int i = 0; i < 3; i++) {      // B: 12 chunks of 8 rows
            int ch = w * 3 + i;
            int row = ch * 8 + src_row;
            async16(woT + (size_t)(n0 + row) * NC + k0 + cbs * 8, sB + ch * 512);
        }
    };

    stage(0, 0);
    int cur = 0;
    f32x4 acc[2][3] = {};
    for (int k0 = 0; k0 < NC; k0 += 64) {
        __syncthreads();
        if (k0 + 64 < NC) stage(k0 + 64, cur ^ 1);
        const u16* sA = smem + cur * 10240;
        const u16* sB = sA + 4096;
#pragma unroll
        for (int s = 0; s < 2; s++) {
            const int j8 = ((s * 4 + lq) ^ swz) * 8;
            bf16x8 af[2], bf[3];
#pragma unroll
            for (int i = 0; i < 2; i++)
                af[i] = *(const bf16x8*)&sA[(wr + i * 16 + lr) * 64 + j8];
#pragma unroll
            for (int i = 0; i < 3; i++)
                bf[i] = *(const bf16x8*)&sB[(wc + i * 16 + lr) * 64 + j8];
#pragma unroll
            for (int mt = 0; mt < 2; mt++)
#pragma unroll
                for (int nt = 0; nt < 3; nt++)
                    acc[mt][nt] = __builtin_amdgcn_mfma_f32_16x16x32_bf16(
                        af[mt], bf[nt], acc[mt][nt], 0, 0, 0);
        }
        cur ^= 1;
    }
#pragma unroll
    for (int mt = 0; mt < 2; mt++)
#pragma unroll
        for (int nt = 0; nt < 3; nt++)
#pragma unroll
            for (int r = 0; r < 4; r++)
                out[(size_t)(row0 + wr + mt * 16 + lq * 4 + r) * DD + n0 + wc + nt * 16 + lr] =
                    acc[mt][nt][r];
}

}  // namespace

extern "C" void kernel_launch(void* const* d_in, const int* in_sizes, int n_in,
                              void* d_out, int out_size, void* d_ws, size_t ws_size,
                              hipStream_t stream) {
    const float* x   = (const float*)d_in[0];
    const float* W_Q = (const float*)d_in[1];
    const float* W_K = (const float*)d_in[2];
    const float* W_V = (const float*)d_in[3];
    const float* W_O = (const float*)d_in[4];
    const float* b_Q = (const float*)d_in[5];
    const float* b_K = (const float*)d_in[6];
    const float* b_V = (const float*)d_in[7];
    const float* Wgq = (const float*)d_in[8];
    const float* Wgk = (const float*)d_in[9];
    const float* bgq = (const float*)d_in[10];
    const float* bgk = (const float*)d_in[11];
    float* out = (float*)d_out;

    char* wsb = (char*)d_ws;
    auto alloc = [&](size_t bytes) -> char* {
        char* p = wsb;
        wsb += (bytes + 255) & ~(size_t)255;
        return p;
    };
    float* invV  = (float*)alloc((size_t)NC * 4);
    float* invO  = (float*)alloc((size_t)NC * 4);
    float* biasp = (float*)alloc((size_t)NQKV * 4);
    float* qg    = (float*)alloc((size_t)RR * HH * 4);
    float* kg    = (float*)alloc((size_t)RR * HH * 4);
    u16* xb      = (u16*)alloc((size_t)RR * DD * 2);
    u16* wT      = (u16*)alloc((size_t)NTOT * DD * 2);
    u16* woT     = (u16*)alloc((size_t)DD * NC * 2);
    u16* qb      = (u16*)alloc((size_t)RR * 64 * HH * 2);
    u16* kb      = (u16*)alloc((size_t)RR * 64 * HH * 2);
    u16* vtb     = (u16*)alloc((size_t)RR * 64 * HH * 2);
    u16* zb      = (u16*)alloc((size_t)RR * NC * 2);

    prep_a_kernel<<<NC + RR * DD / 4 / 256, 256, 0, stream>>>(
        W_V, W_O, invV, invO, x, xb);
    prep_b_kernel<<<1298, 256, 0, stream>>>(
        W_Q, W_K, W_V, invV, wT, W_O, woT, Wgq, Wgk, b_Q, b_K, b_V, biasp);
    qkv_gemm_kernel<<<NTOT / 128 * (RR / 128), 256, 0, stream>>>(
        xb, wT, biasp, bgq, bgk, qb, kb, vtb, qg, kg);
    attn_kernel<<<768, 256, 0, stream>>>(
        qb, kb, vtb, qg, kg, invO, zb);
    out_gemm_kernel<<<512, 256, 0, stream>>>(zb, woT, out);
}